// Round 1
// 1835.297 us; speedup vs baseline: 1.2333x; 1.2333x over previous
//
#include <hip/hip_runtime.h>
#include <hip/hip_bf16.h>
#include <math.h>

typedef __hip_bfloat16 bf16;

// Problem constants (fixed by reference)
#define B_      8
#define S_      2048
#define DIN     1024
#define DSTATE  1024
#define H_      16
#define DH_     64
#define PROJ4   4096   // 4*DSTATE

// ---------------------------------------------------------------------------
// bf16 <-> f32 helpers (bit-level, RNE for store)
// ---------------------------------------------------------------------------
__device__ __forceinline__ unsigned short f2bf(float f) {
    unsigned int x = __float_as_uint(f);
    x += 0x7FFFu + ((x >> 16) & 1u);   // round-to-nearest-even
    return (unsigned short)(x >> 16);
}

__device__ __forceinline__ float4 load4(const float* p) { return *(const float4*)p; }
__device__ __forceinline__ float4 load4(const bf16* p) {
    uint2 u = *(const uint2*)p;    // 4 bf16 = 8 bytes
    float4 r;
    r.x = __uint_as_float((u.x & 0xFFFFu) << 16);
    r.y = __uint_as_float(u.x & 0xFFFF0000u);
    r.z = __uint_as_float((u.y & 0xFFFFu) << 16);
    r.w = __uint_as_float(u.y & 0xFFFF0000u);
    return r;
}
__device__ __forceinline__ void store4(float* p, float4 v) { *(float4*)p = v; }
__device__ __forceinline__ void store4(bf16* p, float4 v) {
    uint2 u;
    u.x = (unsigned int)f2bf(v.x) | ((unsigned int)f2bf(v.y) << 16);
    u.y = (unsigned int)f2bf(v.z) | ((unsigned int)f2bf(v.w) << 16);
    *(uint2*)p = u;
}

// ---------------------------------------------------------------------------
// MFMA bf16 GEMM: C[M,N] = A[M,K] @ B[K,N]; A row stride lda; B,C dense.
// 128x128 tile, BK=32, 256 threads = 4 waves (2x2), each wave 64x64 via a
// 4x4 grid of mfma_f32_16x16x32_bf16. fp32 operands converted to bf16 during
// LDS staging. (Unchanged — recur is this round's target.)
// ---------------------------------------------------------------------------
typedef __attribute__((ext_vector_type(8))) short bf16x8;
typedef __attribute__((ext_vector_type(4))) float f32x4;
typedef __attribute__((ext_vector_type(2))) float f32x2;
typedef __attribute__((ext_vector_type(4))) short short4v;

template <typename TA>
__device__ __forceinline__ void load_a4(const TA* p, float out[4]);
template <>
__device__ __forceinline__ void load_a4<float>(const float* p, float out[4]) {
    float4 v = *(const float4*)p;
    out[0] = v.x; out[1] = v.y; out[2] = v.z; out[3] = v.w;
}
template <>
__device__ __forceinline__ void load_a4<bf16>(const bf16* p, float out[4]) {
    float4 v = load4(p);
    out[0] = v.x; out[1] = v.y; out[2] = v.z; out[3] = v.w;
}

template <typename TA, typename TC>
__global__ __launch_bounds__(256) void gemm_mfma(const TA* __restrict__ A,
                                                 const float* __restrict__ Bm,
                                                 TC* __restrict__ C,
                                                 int M, int N, int K, int lda) {
    __shared__ short As[128][40];   // As[m][k], k contiguous
    __shared__ short Bs[128][40];   // Bs[n][k], k contiguous (B transposed)

    const int tid = threadIdx.x;
    const int m0 = blockIdx.y * 128;
    const int n0 = blockIdx.x * 128;

    const int saM = tid >> 1;              // 0..127
    const int saK = (tid & 1) * 16;        // 0 or 16
    const int sbK = tid >> 3;              // 0..31
    const int sbN = (tid & 7) * 16;        // 0..112

    const int wid = tid >> 6;
    const int wx = wid & 1, wy = wid >> 1; // 2x2 wave grid
    const int lane = tid & 63;
    const int c16 = lane & 15;
    const int quad = lane >> 4;

    const TA* Aptr = A + (size_t)(m0 + saM) * lda + saK;
    const float* Bptr = Bm + (size_t)sbK * N + n0 + sbN;

    f32x4 acc[4][4];
    #pragma unroll
    for (int i = 0; i < 4; ++i)
        #pragma unroll
        for (int j = 0; j < 4; ++j) acc[i][j] = (f32x4){0.f, 0.f, 0.f, 0.f};

    float ra[4][4];
    float rb[4][4];
    #pragma unroll
    for (int i = 0; i < 4; ++i) load_a4<TA>(Aptr + i * 4, ra[i]);
    #pragma unroll
    for (int i = 0; i < 4; ++i) {
        float4 v = load4(Bptr + i * 4);
        rb[i][0] = v.x; rb[i][1] = v.y; rb[i][2] = v.z; rb[i][3] = v.w;
    }

    for (int k0 = 0; k0 < K; k0 += 32) {
        __syncthreads();
        #pragma unroll
        for (int i = 0; i < 4; ++i) {
            short4v pk = { (short)f2bf(ra[i][0]), (short)f2bf(ra[i][1]),
                           (short)f2bf(ra[i][2]), (short)f2bf(ra[i][3]) };
            *(short4v*)&As[saM][saK + i * 4] = pk;
        }
        #pragma unroll
        for (int i = 0; i < 4; ++i)
            #pragma unroll
            for (int j = 0; j < 4; ++j)
                Bs[sbN + i * 4 + j][sbK] = (short)f2bf(rb[i][j]);
        __syncthreads();

        if (k0 + 32 < K) {
            #pragma unroll
            for (int i = 0; i < 4; ++i) load_a4<TA>(Aptr + k0 + 32 + i * 4, ra[i]);
            #pragma unroll
            for (int i = 0; i < 4; ++i) {
                float4 v = load4(Bptr + (size_t)(k0 + 32) * N + i * 4);
                rb[i][0] = v.x; rb[i][1] = v.y; rb[i][2] = v.z; rb[i][3] = v.w;
            }
        }

        bf16x8 af[4], bfr[4];
        #pragma unroll
        for (int mt = 0; mt < 4; ++mt)
            af[mt] = *(const bf16x8*)&As[wy * 64 + mt * 16 + c16][quad * 8];
        #pragma unroll
        for (int nt = 0; nt < 4; ++nt)
            bfr[nt] = *(const bf16x8*)&Bs[wx * 64 + nt * 16 + c16][quad * 8];

        #pragma unroll
        for (int mt = 0; mt < 4; ++mt)
            #pragma unroll
            for (int nt = 0; nt < 4; ++nt)
                acc[mt][nt] = __builtin_amdgcn_mfma_f32_16x16x32_bf16(
                    af[mt], bfr[nt], acc[mt][nt], 0, 0, 0);
    }

    #pragma unroll
    for (int mt = 0; mt < 4; ++mt) {
        #pragma unroll
        for (int r = 0; r < 4; ++r) {
            int row = m0 + wy * 64 + mt * 16 + quad * 4 + r;
            TC* cp = C + (size_t)row * N + n0 + wx * 64;
            #pragma unroll
            for (int nt = 0; nt < 4; ++nt)
                cp[nt * 16 + c16] = (TC)acc[mt][nt][r];
        }
    }
}

// ---------------------------------------------------------------------------
// Recurrence v2: ONE wave per (b,h) chain. Zero barriers, zero LDS.
//  - Lane e owns h[e]; h[d] broadcasts via v_readlane (compile-time lanes).
//  - All of Wr/Wf/Wc live in VGPRs (192 regs); r/f matvecs packed as f32x2
//    so one broadcast feeds both gates (v_pk_fma_f32 when available).
//  - x inputs prefetched 4 steps ahead into a statically-indexed register
//    ring (loop unrolled by 4); h stored to global fire-and-forget.
// Rationale: the previous 4-wave split spent ~1800 of ~1970 cycles/step on
// the two LDS-reduce barriers. This version is pure-VALU issue-bound,
// ~290 VALU ops/step ≈ 580 cycles.
// ---------------------------------------------------------------------------
__device__ __forceinline__ float lane_bcast(float v, int lane) {
    return __int_as_float(__builtin_amdgcn_readlane(__float_as_int(v), lane));
}

__global__ __launch_bounds__(64, 1) void recur_kernel(bf16* __restrict__ proj,
                                                      const float* __restrict__ sw) {
    const int e = threadIdx.x & 63;
    const int bh = blockIdx.x;              // 0..127
    const int b = bh >> 4;
    const int h = bh & 15;

    // Weight columns for this lane's output dim e: W[h][d][e], d stride 64.
    const float* Wc_p = sw + (size_t)h * 4096 + e;
    const float* Wf_p = Wc_p + (size_t)16 * 4096;
    const float* Wr_p = Wc_p + (size_t)32 * 4096;

    f32x2 wrf[64];   // (Wr[d][e], Wf[d][e]) pairs -> v_pk_fma_f32
    float wc[64];
    #pragma unroll
    for (int d = 0; d < 64; ++d) {
        f32x2 v;
        v.x = Wr_p[(size_t)d * 64];
        v.y = Wf_p[(size_t)d * 64];
        wrf[d] = v;
        wc[d] = Wc_p[(size_t)d * 64];
    }

    bf16* xi_p = proj + (size_t)b * S_ * PROJ4 + h * 64 + e;   // cols [0:1024)
    const bf16* xf_p = xi_p + 1024;
    const bf16* xr_p = xi_p + 2048;

    // Register prefetch ring, distance 4 steps (~1000 ns ahead; covers HBM).
    float rxi[4], rxf[4], rxr[4];
    #pragma unroll
    for (int u = 0; u < 4; ++u) {
        size_t o = (size_t)u * PROJ4;
        rxi[u] = __bfloat162float(xi_p[o]);
        rxf[u] = __bfloat162float(xf_p[o]);
        rxr[u] = __bfloat162float(xr_p[o]);
    }

    float hreg = 0.0f;   // lane e holds h[e]

    auto step = [&](int t, int u, bool refill) __attribute__((always_inline)) {
        float xi0 = rxi[u], xf0 = rxf[u], xr0 = rxr[u];
        if (refill) {
            size_t o = (size_t)(t + 4) * PROJ4;
            rxi[u] = __bfloat162float(xi_p[o]);
            rxf[u] = __bfloat162float(xf_p[o]);
            rxr[u] = __bfloat162float(xr_p[o]);
        }

        // Phase 1: r/f matvecs, shared h broadcasts, packed f32x2 FMAs.
        f32x2 a0 = {0.f, 0.f}, a1 = {0.f, 0.f}, a2 = {0.f, 0.f}, a3 = {0.f, 0.f};
        #pragma unroll
        for (int d = 0; d < 64; d += 4) {
            float h0 = lane_bcast(hreg, d);
            float h1 = lane_bcast(hreg, d + 1);
            float h2 = lane_bcast(hreg, d + 2);
            float h3 = lane_bcast(hreg, d + 3);
#if __has_builtin(__builtin_elementwise_fma)
            f32x2 v0 = {h0, h0}, v1 = {h1, h1}, v2 = {h2, h2}, v3 = {h3, h3};
            a0 = __builtin_elementwise_fma(v0, wrf[d],     a0);
            a1 = __builtin_elementwise_fma(v1, wrf[d + 1], a1);
            a2 = __builtin_elementwise_fma(v2, wrf[d + 2], a2);
            a3 = __builtin_elementwise_fma(v3, wrf[d + 3], a3);
#else
            a0.x = fmaf(h0, wrf[d].x,     a0.x); a0.y = fmaf(h0, wrf[d].y,     a0.y);
            a1.x = fmaf(h1, wrf[d + 1].x, a1.x); a1.y = fmaf(h1, wrf[d + 1].y, a1.y);
            a2.x = fmaf(h2, wrf[d + 2].x, a2.x); a2.y = fmaf(h2, wrf[d + 2].y, a2.y);
            a3.x = fmaf(h3, wrf[d + 3].x, a3.x); a3.y = fmaf(h3, wrf[d + 3].y, a3.y);
#endif
        }
        f32x2 srf = (a0 + a1) + (a2 + a3);
        float sr = xr0 + srf.x;
        float sf = xf0 + srf.y;
        float r = 1.f / (1.f + __expf(-sr));
        float f = 1.f / (1.f + __expf(-sf));

        // Phase 2: c matvec on (r .* h).
        float rh = r * hreg;
        float c0 = 0.f, c1 = 0.f, c2 = 0.f, c3 = 0.f;
        #pragma unroll
        for (int d = 0; d < 64; d += 4) {
            c0 = fmaf(lane_bcast(rh, d),     wc[d],     c0);
            c1 = fmaf(lane_bcast(rh, d + 1), wc[d + 1], c1);
            c2 = fmaf(lane_bcast(rh, d + 2), wc[d + 2], c2);
            c3 = fmaf(lane_bcast(rh, d + 3), wc[d + 3], c3);
        }
        float sc = xi0 + (c0 + c1) + (c2 + c3);
        sc = fminf(fmaxf(sc, -15.f), 15.f);
        float ex = __expf(-2.f * sc);
        float cc = (1.f - ex) / (1.f + ex);                 // tanh

        hreg = f * hreg + (1.f - f) * cc;

        // h out (overwrite xi column block); fire-and-forget, coalesced 128B.
        xi_p[(size_t)t * PROJ4] = __float2bfloat16(hreg);
    };

    for (int t0 = 0; t0 + 4 < S_; t0 += 4) {
        #pragma unroll
        for (int u = 0; u < 4; ++u) step(t0 + u, u, true);
    }
    #pragma unroll
    for (int u = 0; u < 4; ++u) step(S_ - 4 + u, u, false);
}

// ---------------------------------------------------------------------------
// Gated RMSNorm in place over proj cols [0:1024).
// ---------------------------------------------------------------------------
__global__ __launch_bounds__(256) void gate_norm_kernel(bf16* __restrict__ proj,
                                                        const float* __restrict__ nw) {
    const int row = blockIdx.x;
    const int tid = threadIdx.x;
    __shared__ float red[4];

    bf16* hp = proj + (size_t)row * PROJ4;
    const bf16* gp = hp + 3 * DSTATE;

    float4 hv = load4(hp + tid * 4);
    float4 gv = load4(gp + tid * 4);

    float v0 = hv.x * (gv.x / (1.f + __expf(-gv.x)));
    float v1 = hv.y * (gv.y / (1.f + __expf(-gv.y)));
    float v2 = hv.z * (gv.z / (1.f + __expf(-gv.z)));
    float v3 = hv.w * (gv.w / (1.f + __expf(-gv.w)));

    float ss = v0 * v0 + v1 * v1 + v2 * v2 + v3 * v3;
    #pragma unroll
    for (int mask = 32; mask >= 1; mask >>= 1)
        ss += __shfl_xor(ss, mask, 64);

    const int wid = tid >> 6;
    if ((tid & 63) == 0) red[wid] = ss;
    __syncthreads();
    float tot = red[0] + red[1] + red[2] + red[3];
    float scale = rsqrtf(tot * (1.0f / (float)DSTATE) + 1e-6f);

    float4 nv = *(const float4*)(nw + tid * 4);
    float4 y;
    y.x = v0 * scale * nv.x;
    y.y = v1 * scale * nv.y;
    y.z = v2 * scale * nv.z;
    y.w = v3 * scale * nv.w;
    store4(hp + tid * 4, y);
}

// ---------------------------------------------------------------------------
extern "C" void kernel_launch(void* const* d_in, const int* in_sizes, int n_in,
                              void* d_out, int out_size, void* d_ws, size_t ws_size,
                              hipStream_t stream) {
    const float* x     = (const float*)d_in[0];   // [B,S,DIN]
    const float* w_in  = (const float*)d_in[1];   // [DIN, 4*DSTATE]
    const float* sw    = (const float*)d_in[2];   // [3H, DH, DH]
    const float* nw    = (const float*)d_in[3];   // [DSTATE]
    const float* w_out = (const float*)d_in[4];   // [DSTATE, DOUT]
    float* out = (float*)d_out;

    bf16* proj = (bf16*)d_ws;    // [B*S, 4096] bf16 = 134 MB (only ws use)

    // 1) input projection GEMM (MFMA bf16): [16384,1024] @ [1024,4096] -> bf16
    dim3 g1(PROJ4 / 128, (B_ * S_) / 128);
    gemm_mfma<float, bf16><<<g1, 256, 0, stream>>>(x, w_in, proj,
                                                   B_ * S_, PROJ4, DIN, DIN);

    // 2) sequential gated recurrence: 1 wave per (b,h) chain, no barriers
    recur_kernel<<<128, 64, 0, stream>>>(proj, sw);

    // 3) gate + rmsnorm in place over cols 0:1024
    gate_norm_kernel<<<B_ * S_, 256, 0, stream>>>(proj, nw);

    // 4) output projection GEMM (MFMA bf16): y(bf16, lda=4096) @ [1024,1024] -> f32
    dim3 g2(DSTATE / 128, (B_ * S_) / 128);
    gemm_mfma<bf16, float><<<g2, 256, 0, stream>>>(proj, w_out, out,
                                                   B_ * S_, DSTATE, DSTATE, PROJ4);
}

// Round 2
// 1680.492 us; speedup vs baseline: 1.3469x; 1.0921x over previous
//
#include <hip/hip_runtime.h>
#include <hip/hip_bf16.h>
#include <math.h>

typedef __hip_bfloat16 bf16;

// Problem constants (fixed by reference)
#define B_      8
#define S_      2048
#define DIN     1024
#define DSTATE  1024
#define H_      16
#define DH_     64
#define PROJ4   4096   // 4*DSTATE

// ---------------------------------------------------------------------------
// bf16 <-> f32 helpers (bit-level, RNE for store)
// ---------------------------------------------------------------------------
__device__ __forceinline__ unsigned short f2bf(float f) {
    unsigned int x = __float_as_uint(f);
    x += 0x7FFFu + ((x >> 16) & 1u);   // round-to-nearest-even
    return (unsigned short)(x >> 16);
}

__device__ __forceinline__ float4 load4(const float* p) { return *(const float4*)p; }
__device__ __forceinline__ float4 load4(const bf16* p) {
    uint2 u = *(const uint2*)p;    // 4 bf16 = 8 bytes
    float4 r;
    r.x = __uint_as_float((u.x & 0xFFFFu) << 16);
    r.y = __uint_as_float(u.x & 0xFFFF0000u);
    r.z = __uint_as_float((u.y & 0xFFFFu) << 16);
    r.w = __uint_as_float(u.y & 0xFFFF0000u);
    return r;
}
__device__ __forceinline__ void store4(float* p, float4 v) { *(float4*)p = v; }
__device__ __forceinline__ void store4(bf16* p, float4 v) {
    uint2 u;
    u.x = (unsigned int)f2bf(v.x) | ((unsigned int)f2bf(v.y) << 16);
    u.y = (unsigned int)f2bf(v.z) | ((unsigned int)f2bf(v.w) << 16);
    *(uint2*)p = u;
}

// ---------------------------------------------------------------------------
// MFMA bf16 GEMM (unchanged — recur is this round's target).
// ---------------------------------------------------------------------------
typedef __attribute__((ext_vector_type(8))) short bf16x8;
typedef __attribute__((ext_vector_type(4))) float f32x4;
typedef __attribute__((ext_vector_type(2))) float f32x2;
typedef __attribute__((ext_vector_type(4))) short short4v;

template <typename TA>
__device__ __forceinline__ void load_a4(const TA* p, float out[4]);
template <>
__device__ __forceinline__ void load_a4<float>(const float* p, float out[4]) {
    float4 v = *(const float4*)p;
    out[0] = v.x; out[1] = v.y; out[2] = v.z; out[3] = v.w;
}
template <>
__device__ __forceinline__ void load_a4<bf16>(const bf16* p, float out[4]) {
    float4 v = load4(p);
    out[0] = v.x; out[1] = v.y; out[2] = v.z; out[3] = v.w;
}

template <typename TA, typename TC>
__global__ __launch_bounds__(256) void gemm_mfma(const TA* __restrict__ A,
                                                 const float* __restrict__ Bm,
                                                 TC* __restrict__ C,
                                                 int M, int N, int K, int lda) {
    __shared__ short As[128][40];   // As[m][k], k contiguous
    __shared__ short Bs[128][40];   // Bs[n][k], k contiguous (B transposed)

    const int tid = threadIdx.x;
    const int m0 = blockIdx.y * 128;
    const int n0 = blockIdx.x * 128;

    const int saM = tid >> 1;              // 0..127
    const int saK = (tid & 1) * 16;        // 0 or 16
    const int sbK = tid >> 3;              // 0..31
    const int sbN = (tid & 7) * 16;        // 0..112

    const int wid = tid >> 6;
    const int wx = wid & 1, wy = wid >> 1; // 2x2 wave grid
    const int lane = tid & 63;
    const int c16 = lane & 15;
    const int quad = lane >> 4;

    const TA* Aptr = A + (size_t)(m0 + saM) * lda + saK;
    const float* Bptr = Bm + (size_t)sbK * N + n0 + sbN;

    f32x4 acc[4][4];
    #pragma unroll
    for (int i = 0; i < 4; ++i)
        #pragma unroll
        for (int j = 0; j < 4; ++j) acc[i][j] = (f32x4){0.f, 0.f, 0.f, 0.f};

    float ra[4][4];
    float rb[4][4];
    #pragma unroll
    for (int i = 0; i < 4; ++i) load_a4<TA>(Aptr + i * 4, ra[i]);
    #pragma unroll
    for (int i = 0; i < 4; ++i) {
        float4 v = load4(Bptr + i * 4);
        rb[i][0] = v.x; rb[i][1] = v.y; rb[i][2] = v.z; rb[i][3] = v.w;
    }

    for (int k0 = 0; k0 < K; k0 += 32) {
        __syncthreads();
        #pragma unroll
        for (int i = 0; i < 4; ++i) {
            short4v pk = { (short)f2bf(ra[i][0]), (short)f2bf(ra[i][1]),
                           (short)f2bf(ra[i][2]), (short)f2bf(ra[i][3]) };
            *(short4v*)&As[saM][saK + i * 4] = pk;
        }
        #pragma unroll
        for (int i = 0; i < 4; ++i)
            #pragma unroll
            for (int j = 0; j < 4; ++j)
                Bs[sbN + i * 4 + j][sbK] = (short)f2bf(rb[i][j]);
        __syncthreads();

        if (k0 + 32 < K) {
            #pragma unroll
            for (int i = 0; i < 4; ++i) load_a4<TA>(Aptr + k0 + 32 + i * 4, ra[i]);
            #pragma unroll
            for (int i = 0; i < 4; ++i) {
                float4 v = load4(Bptr + (size_t)(k0 + 32) * N + i * 4);
                rb[i][0] = v.x; rb[i][1] = v.y; rb[i][2] = v.z; rb[i][3] = v.w;
            }
        }

        bf16x8 af[4], bfr[4];
        #pragma unroll
        for (int mt = 0; mt < 4; ++mt)
            af[mt] = *(const bf16x8*)&As[wy * 64 + mt * 16 + c16][quad * 8];
        #pragma unroll
        for (int nt = 0; nt < 4; ++nt)
            bfr[nt] = *(const bf16x8*)&Bs[wx * 64 + nt * 16 + c16][quad * 8];

        #pragma unroll
        for (int mt = 0; mt < 4; ++mt)
            #pragma unroll
            for (int nt = 0; nt < 4; ++nt)
                acc[mt][nt] = __builtin_amdgcn_mfma_f32_16x16x32_bf16(
                    af[mt], bfr[nt], acc[mt][nt], 0, 0, 0);
    }

    #pragma unroll
    for (int mt = 0; mt < 4; ++mt) {
        #pragma unroll
        for (int r = 0; r < 4; ++r) {
            int row = m0 + wy * 64 + mt * 16 + quad * 4 + r;
            TC* cp = C + (size_t)row * N + n0 + wx * 64;
            #pragma unroll
            for (int nt = 0; nt < 4; ++nt)
                cp[nt * 16 + c16] = (TC)acc[mt][nt][r];
        }
    }
}

// ---------------------------------------------------------------------------
// Recurrence v3: ONE wave per (b,h) chain; weights in NAMED registers
// (macro-generated f32x2 variables — cannot go to scratch, unlike arrays:
// R1's VGPR_Count=124 proved the array version spilled all 192 weights);
// h-broadcast via wave-uniform ds_read_b128 (1 instr = 4 broadcast values,
// pairs feed v_pk_fma_f32 directly). Zero barriers, zero readlanes.
// ---------------------------------------------------------------------------
#define RPT32(M) M(0) M(1) M(2) M(3) M(4) M(5) M(6) M(7) M(8) M(9) M(10) M(11) \
  M(12) M(13) M(14) M(15) M(16) M(17) M(18) M(19) M(20) M(21) M(22) M(23) \
  M(24) M(25) M(26) M(27) M(28) M(29) M(30) M(31)

__global__ __launch_bounds__(64, 1) void recur_kernel(bf16* __restrict__ proj,
                                                      const float* __restrict__ sw) {
    const int e = threadIdx.x & 63;
    const int bh = blockIdx.x;              // 0..127
    const int b = bh >> 4;
    const int h = bh & 15;

    __shared__ __align__(16) float lds_h[64];
    __shared__ __align__(16) float lds_rh[64];

    // Weight columns for lane e: W[h][d][e], d stride 64 floats.
    const float* Wc_p = sw + (size_t)h * 4096 + e;
    const float* Wf_p = Wc_p + (size_t)16 * 4096;
    const float* Wr_p = Wc_p + (size_t)32 * 4096;

    // 96 named f32x2: (W[2i][e], W[2i+1][e]) pairs for pk_fma.
    #define DECLW(i) f32x2 wr##i, wf##i, wc##i;
    RPT32(DECLW)
    #undef DECLW
    #define LOADW(i) \
        wr##i = (f32x2){Wr_p[(2*i) * 64], Wr_p[(2*i+1) * 64]}; \
        wf##i = (f32x2){Wf_p[(2*i) * 64], Wf_p[(2*i+1) * 64]}; \
        wc##i = (f32x2){Wc_p[(2*i) * 64], Wc_p[(2*i+1) * 64]};
    RPT32(LOADW)
    #undef LOADW

    bf16* xi_p = proj + (size_t)b * S_ * PROJ4 + h * 64 + e;   // cols [0:1024)

    // Register prefetch ring (named vectors, literal subscripts only).
    f32x4 rxi, rxf, rxr;
    #define PRELOAD(U) { const bf16* p = xi_p + (size_t)(U) * PROJ4; \
        rxi[U] = __bfloat162float(p[0]); \
        rxf[U] = __bfloat162float(p[1024]); \
        rxr[U] = __bfloat162float(p[2048]); }
    PRELOAD(0) PRELOAD(1) PRELOAD(2) PRELOAD(3)
    #undef PRELOAD

    float hreg = 0.0f;       // lane e holds h[e]
    lds_h[e] = 0.0f;         // seed broadcast buffer (h0 = 0)

    const bf16* ld = xi_p + (size_t)4 * PROJ4;  // refill ptr (t+4)
    bf16*       st = xi_p;                      // store ptr (t)

    // Phase-1 body: hb = broadcast of h[4J..4J+3]; accumulate r & f gates.
    #define P1(J, A, Bq) { \
        f32x4 hb = *(const f32x4*)&lds_h[4 * (J)]; \
        aR0 = __builtin_elementwise_fma(hb.lo, wr##A, aR0); \
        aR1 = __builtin_elementwise_fma(hb.hi, wr##Bq, aR1); \
        aF0 = __builtin_elementwise_fma(hb.lo, wf##A, aF0); \
        aF1 = __builtin_elementwise_fma(hb.hi, wf##Bq, aF1); }
    #define P1_ALL \
        P1(0,0,1)   P1(1,2,3)   P1(2,4,5)   P1(3,6,7) \
        P1(4,8,9)   P1(5,10,11) P1(6,12,13) P1(7,14,15) \
        P1(8,16,17) P1(9,18,19) P1(10,20,21) P1(11,22,23) \
        P1(12,24,25) P1(13,26,27) P1(14,28,29) P1(15,30,31)

    #define P2(J, A, Bq) { \
        f32x4 qb = *(const f32x4*)&lds_rh[4 * (J)]; \
        aC0 = __builtin_elementwise_fma(qb.lo, wc##A, aC0); \
        aC1 = __builtin_elementwise_fma(qb.hi, wc##Bq, aC1); }
    #define P2_ALL \
        P2(0,0,1)   P2(1,2,3)   P2(2,4,5)   P2(3,6,7) \
        P2(4,8,9)   P2(5,10,11) P2(6,12,13) P2(7,14,15) \
        P2(8,16,17) P2(9,18,19) P2(10,20,21) P2(11,22,23) \
        P2(12,24,25) P2(13,26,27) P2(14,28,29) P2(15,30,31)

    #define STEP(U, REFILL) { \
        float xi0 = rxi[U], xf0 = rxf[U], xr0 = rxr[U]; \
        if (REFILL) { \
            const bf16* p = ld + (size_t)(U) * PROJ4; \
            rxi[U] = __bfloat162float(p[0]); \
            rxf[U] = __bfloat162float(p[1024]); \
            rxr[U] = __bfloat162float(p[2048]); \
        } \
        f32x2 aR0 = {0.f, 0.f}, aR1 = {0.f, 0.f}; \
        f32x2 aF0 = {0.f, 0.f}, aF1 = {0.f, 0.f}; \
        P1_ALL \
        f32x2 aR = aR0 + aR1, aF = aF0 + aF1; \
        float sr = xr0 + aR.x + aR.y; \
        float sf = xf0 + aF.x + aF.y; \
        float r = 1.f / (1.f + __expf(-sr)); \
        float f = 1.f / (1.f + __expf(-sf)); \
        float rh = r * hreg; \
        lds_rh[e] = rh; \
        f32x2 aC0 = {0.f, 0.f}, aC1 = {0.f, 0.f}; \
        P2_ALL \
        f32x2 aC = aC0 + aC1; \
        float sc = xi0 + aC.x + aC.y; \
        sc = fminf(fmaxf(sc, -15.f), 15.f); \
        float ex = __expf(-2.f * sc); \
        float cc = (1.f - ex) / (1.f + ex); \
        hreg = f * hreg + (1.f - f) * cc; \
        lds_h[e] = hreg; \
        st[(size_t)(U) * PROJ4] = __float2bfloat16(hreg); \
    }

    for (int t0 = 0; t0 < S_ - 4; t0 += 4) {
        STEP(0, 1) STEP(1, 1) STEP(2, 1) STEP(3, 1)
        ld += (size_t)4 * PROJ4;
        st += (size_t)4 * PROJ4;
    }
    STEP(0, 0) STEP(1, 0) STEP(2, 0) STEP(3, 0)

    #undef STEP
    #undef P1
    #undef P1_ALL
    #undef P2
    #undef P2_ALL
}

// ---------------------------------------------------------------------------
// Gated RMSNorm in place over proj cols [0:1024).
// ---------------------------------------------------------------------------
__global__ __launch_bounds__(256) void gate_norm_kernel(bf16* __restrict__ proj,
                                                        const float* __restrict__ nw) {
    const int row = blockIdx.x;
    const int tid = threadIdx.x;
    __shared__ float red[4];

    bf16* hp = proj + (size_t)row * PROJ4;
    const bf16* gp = hp + 3 * DSTATE;

    float4 hv = load4(hp + tid * 4);
    float4 gv = load4(gp + tid * 4);

    float v0 = hv.x * (gv.x / (1.f + __expf(-gv.x)));
    float v1 = hv.y * (gv.y / (1.f + __expf(-gv.y)));
    float v2 = hv.z * (gv.z / (1.f + __expf(-gv.z)));
    float v3 = hv.w * (gv.w / (1.f + __expf(-gv.w)));

    float ss = v0 * v0 + v1 * v1 + v2 * v2 + v3 * v3;
    #pragma unroll
    for (int mask = 32; mask >= 1; mask >>= 1)
        ss += __shfl_xor(ss, mask, 64);

    const int wid = tid >> 6;
    if ((tid & 63) == 0) red[wid] = ss;
    __syncthreads();
    float tot = red[0] + red[1] + red[2] + red[3];
    float scale = rsqrtf(tot * (1.0f / (float)DSTATE) + 1e-6f);

    float4 nv = *(const float4*)(nw + tid * 4);
    float4 y;
    y.x = v0 * scale * nv.x;
    y.y = v1 * scale * nv.y;
    y.z = v2 * scale * nv.z;
    y.w = v3 * scale * nv.w;
    store4(hp + tid * 4, y);
}

// ---------------------------------------------------------------------------
extern "C" void kernel_launch(void* const* d_in, const int* in_sizes, int n_in,
                              void* d_out, int out_size, void* d_ws, size_t ws_size,
                              hipStream_t stream) {
    const float* x     = (const float*)d_in[0];   // [B,S,DIN]
    const float* w_in  = (const float*)d_in[1];   // [DIN, 4*DSTATE]
    const float* sw    = (const float*)d_in[2];   // [3H, DH, DH]
    const float* nw    = (const float*)d_in[3];   // [DSTATE]
    const float* w_out = (const float*)d_in[4];   // [DSTATE, DOUT]
    float* out = (float*)d_out;

    bf16* proj = (bf16*)d_ws;    // [B*S, 4096] bf16 = 134 MB (only ws use)

    // 1) input projection GEMM (MFMA bf16): [16384,1024] @ [1024,4096] -> bf16
    dim3 g1(PROJ4 / 128, (B_ * S_) / 128);
    gemm_mfma<float, bf16><<<g1, 256, 0, stream>>>(x, w_in, proj,
                                                   B_ * S_, PROJ4, DIN, DIN);

    // 2) sequential gated recurrence: 1 wave per (b,h) chain, weights in regs
    recur_kernel<<<128, 64, 0, stream>>>(proj, sw);

    // 3) gate + rmsnorm in place over cols 0:1024
    gate_norm_kernel<<<B_ * S_, 256, 0, stream>>>(proj, nw);

    // 4) output projection GEMM (MFMA bf16): y(bf16, lda=4096) @ [1024,1024] -> f32
    dim3 g2(DSTATE / 128, (B_ * S_) / 128);
    gemm_mfma<bf16, float><<<g2, 256, 0, stream>>>(proj, w_out, out,
                                                   B_ * S_, DSTATE, DSTATE, PROJ4);
}